// Round 1
// baseline (510.937 us; speedup 1.0000x reference)
//
#include <hip/hip_runtime.h>
#include <cmath>

#define B_    8
#define T_    256
#define V_    32000
#define E_    512
#define OOV_  100
#define VE_   (V_ + OOV_)               // 32100
#define ROWS_ (B_ * T_)                 // 2048
#define NV4_  (V_ / 4)                  // 8000 float4 per row
#define PAD4_ (OOV_ / 4)                // 25 float4 of zero padding
#define TOTAL_ ((size_t)ROWS_ * VE_)    // 65,740,800 floats

// One block (1024 threads) per (b,t) row.
//  - fused pgen dot(2048) + sigmoid
//  - register-resident softmax over V=32000 (single HBM read of logits)
//  - writes pgen * softmax to out_total, zeroes the OOV pad, writes pgen
__global__ __launch_bounds__(1024) void pg_softmax_kernel(
    const float* __restrict__ logits,
    const float* __restrict__ ctx,    // (rows, 512)
    const float* __restrict__ hid,    // (rows, 1024)
    const float* __restrict__ dec,    // (rows, 512)
    const float* __restrict__ pw,     // (2048,)
    const float* __restrict__ pb,     // (1,)
    float* __restrict__ out_total,    // (rows, 32100)
    float* __restrict__ out_pgen)     // (rows,)
{
  const int row  = blockIdx.x;
  const int tid  = threadIdx.x;
  const int lane = tid & 63;
  const int wid  = tid >> 6;          // 16 waves per block
  __shared__ float redA[16];
  __shared__ float redB[16];

  // ---------------- pgen: dot(pre, w) over 2048 features ----------------
  float acc = 0.f;
  #pragma unroll
  for (int k = 0; k < 2; ++k) {
    const int f = tid + (k << 10);
    float pv;
    if (f < 512)       pv = ctx[row * 512 + f];
    else if (f < 1536) pv = hid[row * 1024 + (f - 512)];
    else               pv = dec[row * 512 + (f - 1536)];
    acc += pv * pw[f];
  }
  #pragma unroll
  for (int o = 32; o > 0; o >>= 1) acc += __shfl_xor(acc, o);
  if (lane == 0) redA[wid] = acc;
  __syncthreads();
  if (tid < 16) {
    float x = redA[tid];
    #pragma unroll
    for (int o = 8; o > 0; o >>= 1) x += __shfl_xor(x, o);
    if (tid == 0) redA[0] = x;
  }
  __syncthreads();
  const float pgen = 1.f / (1.f + __expf(-(redA[0] + pb[0])));
  __syncthreads();   // redA gets reused below

  // ---------------- softmax stats, row held in registers ----------------
  const float4* lrow = (const float4*)(logits + (size_t)row * V_);
  float4 v[8];
  float m = -3.0e38f;
  #pragma unroll
  for (int k = 0; k < 8; ++k) {
    const int i = tid + (k << 10);
    if (i < NV4_) {
      const float4 x = lrow[i];
      v[k] = x;
      m = fmaxf(m, fmaxf(fmaxf(x.x, x.y), fmaxf(x.z, x.w)));
    }
  }
  float s = 0.f;
  #pragma unroll
  for (int k = 0; k < 8; ++k) {
    const int i = tid + (k << 10);
    if (i < NV4_) {
      float4 x = v[k];
      x.x = __expf(x.x - m); x.y = __expf(x.y - m);
      x.z = __expf(x.z - m); x.w = __expf(x.w - m);
      s += x.x + x.y + x.z + x.w;
      v[k] = x;                    // stash exp(x - m_local)
    }
  }
  // wave-level (m,s) online merge
  #pragma unroll
  for (int o = 32; o > 0; o >>= 1) {
    const float om = __shfl_xor(m, o);
    const float os = __shfl_xor(s, o);
    const float nm = fmaxf(m, om);
    s = s * __expf(m - nm) + os * __expf(om - nm);
    m = nm;
  }
  if (lane == 0) { redA[wid] = m; redB[wid] = s; }
  __syncthreads();
  if (tid < 16) {
    float mm = redA[tid], ss = redB[tid];
    #pragma unroll
    for (int o = 8; o > 0; o >>= 1) {
      const float om = __shfl_xor(mm, o);
      const float os = __shfl_xor(ss, o);
      const float nm = fmaxf(mm, om);
      ss = ss * __expf(mm - nm) + os * __expf(om - nm);
      mm = nm;
    }
    if (tid == 0) { redA[0] = mm; redB[0] = ss; }
  }
  __syncthreads();
  const float M = redA[0];
  const float S = redB[0];
  // out = exp(x - M)/S * pgen = stash * exp(m_local - M)/S * pgen
  const float scale = pgen * __expf(m - M) / S;

  // ---------------- blended write + OOV pad zeroing ----------------
  float4* orow = (float4*)(out_total + (size_t)row * VE_);
  #pragma unroll
  for (int k = 0; k < 8; ++k) {
    const int i = tid + (k << 10);
    if (i < NV4_) {
      float4 x = v[k];
      x.x *= scale; x.y *= scale; x.z *= scale; x.w *= scale;
      orow[i] = x;
    }
  }
  if (tid < PAD4_) orow[NV4_ + tid] = make_float4(0.f, 0.f, 0.f, 0.f);
  if (tid == 0) out_pgen[row] = pgen;
}

// One thread per (b,t,e): atomic scatter-add of (1-pgen)*attn into out_total.
__global__ __launch_bounds__(256) void scatter_kernel(
    const float* __restrict__ attn,    // (rows, 512)
    const int*   __restrict__ enc,     // (B, 512)
    const float* __restrict__ pgen,    // (rows,)
    float* __restrict__ out_total)     // (rows, 32100)
{
  const int g  = blockIdx.x * 256 + threadIdx.x;  // [0, ROWS_*E_)
  const int e  = g & (E_ - 1);
  const int bt = g >> 9;
  const int b  = bt >> 8;                          // T_ = 256
  const int idx = enc[(b << 9) + e];
  const float add = (1.f - pgen[bt]) * attn[g];
  atomicAdd(out_total + (size_t)bt * VE_ + idx, add);
}

extern "C" void kernel_launch(void* const* d_in, const int* in_sizes, int n_in,
                              void* d_out, int out_size, void* d_ws, size_t ws_size,
                              hipStream_t stream) {
  const float* logits = (const float*)d_in[0];   // (8,256,32000)
  const float* attn   = (const float*)d_in[1];   // (8,256,512)
  const float* hid    = (const float*)d_in[2];   // (8,256,1024)
  const float* dec    = (const float*)d_in[3];   // (8,256,512)
  const float* ctx    = (const float*)d_in[4];   // (8,256,512)
  const int*   enc    = (const int*)d_in[5];     // (8,512)
  const float* pw     = (const float*)d_in[6];   // (1,2048)
  const float* pb     = (const float*)d_in[7];   // (1,)

  float* out_total = (float*)d_out;
  float* out_pgen  = out_total + TOTAL_;

  pg_softmax_kernel<<<ROWS_, 1024, 0, stream>>>(
      logits, ctx, hid, dec, pw, pb, out_total, out_pgen);
  scatter_kernel<<<(ROWS_ * E_) / 256, 256, 0, stream>>>(
      attn, enc, out_pgen, out_total);
}